// Round 5
// baseline (269.138 us; speedup 1.0000x reference)
//
#include <hip/hip_runtime.h>
#include <math.h>

// GeodesicPrototypeClassifier via split-bf16 MFMA — INSTRUMENTED (REP=32).
// Body is identical to round 4; wrapped in a repeat loop with opaque pointers
// so the kernel dispatch becomes visible in rocprof top-5 with counters.
// All writes are idempotent -> output unchanged. True kernel time = dur/32.

typedef __attribute__((ext_vector_type(8))) short bf16x8;
typedef __attribute__((ext_vector_type(4))) float f32x4;

#define K_PROTO 128
#define D_DIM   64
#define BN      64
#define BK      64
#define PAD     72
#define REP     32

__device__ __forceinline__ unsigned f2bfbits(float f) {
    unsigned u = __float_as_uint(f);
    return (u + 0x7fffu + ((u >> 16) & 1u)) >> 16;   // RNE
}
__device__ __forceinline__ void cvt1(float f, short* h, short* l) {
    unsigned hb = f2bfbits(f);
    float lo = f - __uint_as_float(hb << 16);        // exact residual
    *h = (short)hb;
    *l = (short)f2bfbits(lo);
}
__device__ __forceinline__ void cvt8(float4 v0, float4 v1, bf16x8* h8, bf16x8* l8) {
    short hs, ls;
    cvt1(v0.x,&hs,&ls); (*h8)[0]=hs; (*l8)[0]=ls;
    cvt1(v0.y,&hs,&ls); (*h8)[1]=hs; (*l8)[1]=ls;
    cvt1(v0.z,&hs,&ls); (*h8)[2]=hs; (*l8)[2]=ls;
    cvt1(v0.w,&hs,&ls); (*h8)[3]=hs; (*l8)[3]=ls;
    cvt1(v1.x,&hs,&ls); (*h8)[4]=hs; (*l8)[4]=ls;
    cvt1(v1.y,&hs,&ls); (*h8)[5]=hs; (*l8)[5]=ls;
    cvt1(v1.z,&hs,&ls); (*h8)[6]=hs; (*l8)[6]=ls;
    cvt1(v1.w,&hs,&ls); (*h8)[7]=hs; (*l8)[7]=ls;
}

__global__ __launch_bounds__(256) void geodesic_mfma(
    const float* __restrict__ xg,
    const float* __restrict__ pg,
    float* __restrict__ outg)
{
    __shared__ __align__(16) short ph[BK * PAD];
    __shared__ __align__(16) short pl[BK * PAD];
    __shared__ float sp2[BK];
    __shared__ float ssc[BK];
    __shared__ float sx2[BN];

    const int t  = threadIdx.x;
    const int nb = (int)blockIdx.x >> 1;
    const int kb = (int)blockIdx.x & 1;
    const int n0 = nb * BN;
    const int k0 = kb * BK;

    for (int rep = 0; rep < REP; ++rep) {
        // Opaque views: block hoisting/CSE across reps without changing values.
        const float* x = xg;
        const float* p = pg;
        float* out = outg;
        asm volatile("" : "+s"(x), "+s"(p), "+s"(out));

        // ---- stage p block as bf16 hi/lo into LDS ----
        {
            const int row = t >> 2;
            const int dq  = (t & 3) << 4;
            const float* pr = p + (size_t)(k0 + row) * D_DIM + dq;
            #pragma unroll
            for (int hh = 0; hh < 2; ++hh) {
                float4 v0 = *(const float4*)(pr + 8 * hh);
                float4 v1 = *(const float4*)(pr + 8 * hh + 4);
                bf16x8 h8, l8;
                cvt8(v0, v1, &h8, &l8);
                *(bf16x8*)(&ph[row * PAD + dq + 8 * hh]) = h8;
                *(bf16x8*)(&pl[row * PAD + dq + 8 * hh]) = l8;
            }
        }

        // ---- per-row scalars ----
        if (t < BK) {
            const float* pr = p + (size_t)(k0 + t) * D_DIM;
            float s2 = 0.f;
            #pragma unroll
            for (int i = 0; i < 16; ++i) {
                float4 v = *(const float4*)(pr + 4 * i);
                s2 += v.x*v.x + v.y*v.y + v.z*v.z + v.w*v.w;
            }
            float nrm = fmaxf(sqrtf(s2), 1e-15f);
            float sc  = fminf(1.0f, 0.999f / nrm);
            ssc[t] = sc;
            sp2[t] = s2 * sc * sc;
        } else if (t < BK + BN) {
            const int r = t - BK;
            const float* xr = x + (size_t)(n0 + r) * D_DIM;
            float s2 = 0.f;
            #pragma unroll
            for (int i = 0; i < 16; ++i) {
                float4 v = *(const float4*)(xr + 4 * i);
                s2 += v.x*v.x + v.y*v.y + v.z*v.z + v.w*v.w;
            }
            sx2[r] = s2;
        }
        __syncthreads();

        // ---- per-lane x fragments (A operand) from global ----
        const int w    = t >> 6;
        const int lane = t & 63;
        const int q    = lane >> 4;
        const int m16  = lane & 15;

        bf16x8 xh0, xl0, xh1, xl1;
        {
            const float* xr = x + (size_t)(n0 + w * 16 + m16) * D_DIM + q * 8;
            float4 a0 = *(const float4*)(xr);
            float4 a1 = *(const float4*)(xr + 4);
            float4 b0 = *(const float4*)(xr + 32);
            float4 b1 = *(const float4*)(xr + 36);
            cvt8(a0, a1, &xh0, &xl0);
            cvt8(b0, b1, &xh1, &xl1);
        }

        // ---- 4 k-tiles: 6 MFMA each + epilogue ----
        #pragma unroll
        for (int kt = 0; kt < 4; ++kt) {
            const int klocal = kt * 16 + m16;
            const int off    = klocal * PAD + q * 8;
            bf16x8 bh0 = *(const bf16x8*)(&ph[off]);
            bf16x8 bh1 = *(const bf16x8*)(&ph[off + 32]);
            bf16x8 bl0 = *(const bf16x8*)(&pl[off]);
            bf16x8 bl1 = *(const bf16x8*)(&pl[off + 32]);

            f32x4 acc = {0.f, 0.f, 0.f, 0.f};
            acc = __builtin_amdgcn_mfma_f32_16x16x32_bf16(xh0, bh0, acc, 0, 0, 0);
            acc = __builtin_amdgcn_mfma_f32_16x16x32_bf16(xh1, bh1, acc, 0, 0, 0);
            acc = __builtin_amdgcn_mfma_f32_16x16x32_bf16(xh0, bl0, acc, 0, 0, 0);
            acc = __builtin_amdgcn_mfma_f32_16x16x32_bf16(xh1, bl1, acc, 0, 0, 0);
            acc = __builtin_amdgcn_mfma_f32_16x16x32_bf16(xl0, bh0, acc, 0, 0, 0);
            acc = __builtin_amdgcn_mfma_f32_16x16x32_bf16(xl1, bh1, acc, 0, 0, 0);

            const float scv = ssc[klocal];
            const float p2  = sp2[klocal];
            #pragma unroll
            for (int r = 0; r < 4; ++r) {
                const int rl  = w * 16 + q * 4 + r;
                const float x2 = sx2[rl];
                const float xy = acc[r] * scv;
                const float aa = 1.0f - 2.0f * xy + p2;
                const float bb = 1.0f - x2;
                const float den = fmaxf(1.0f - 2.0f * xy + x2 * p2, 1e-15f);
                const float n2 = fmaxf(aa*aa*x2 - 2.0f*aa*bb*xy + bb*bb*p2, 0.0f);
                const float s  = fminf(sqrtf(n2), 0.99999f * den);
                const float l  = __logf(__fdividef(den + s, den - s));
                out[(size_t)(n0 + rl) * K_PROTO + k0 + klocal] = -(l * l);
            }
        }
        __syncthreads();   // protect LDS re-stage of next rep
    }
}

extern "C" void kernel_launch(void* const* d_in, const int* in_sizes, int n_in,
                              void* d_out, int out_size, void* d_ws, size_t ws_size,
                              hipStream_t stream) {
    const float* x = (const float*)d_in[0];   // (16384, 64) f32
    const float* p = (const float*)d_in[1];   // (128, 64) f32
    float* out = (float*)d_out;               // (16384, 128) f32

    dim3 grid((16384 / BN) * (K_PROTO / BK)); // 512 blocks
    dim3 block(256);
    hipLaunchKernelGGL(geodesic_mfma, grid, block, 0, stream, x, p, out);
}

// Round 6
// 65.207 us; speedup vs baseline: 4.1275x; 4.1275x over previous
//
#include <hip/hip_runtime.h>
#include <math.h>

// GeodesicPrototypeClassifier, two-kernel split-bf16 MFMA.
// out[n,k] = -(2*atanh(clamp(z)))^2, z = ||mobius_add(-x_n,p_k)|| (c=1).
// ||num||^2 = a^2*x2 - 2ab*xy + b^2*p2 -> only x2, p2, xy needed.
// xy via MFMA with exact hi/lo bf16 split (xh*ph + xh*pl + xl*ph; dropped
// xl*pl ~ 2^-18). Kernel A converts x,p ONCE into MFMA per-lane fragment
// layout in d_ws (round 5 showed per-block conversion VALU was the limiter:
// VALUBusy 58% @ 2 waves/SIMD). Kernel B: no LDS, no barriers, no cvt.
// Fragment layout (validated round 4): A lane(q=lane>>4,m16=lane&15) holds
// rows m16, d-chunk q*8..+8 (half0) and 32+q*8 (half1); B same with m16=k.
// C/D: col=lane&15(k), row=q*4+r (m89-verified).

typedef __attribute__((ext_vector_type(8))) short bf16x8;
typedef __attribute__((ext_vector_type(4))) float f32x4;

#define K_PROTO 128
#define D_DIM   64

// ws layout (uint4 = one bf16x8 fragment = 16 B):
//  XH0[65536] XH1[65536] XL0[65536] XL1[65536]   (4 MB)  x frags, idx g*64+q*16+m16
//  x2f[16384]                                     (64 KB)
//  PH0[512] PH1[512] PL0[512] PL1[512]            (32 KB) p frags, idx kt*64+q*16+m16
//  p2f[128]
#define XFRAG_N 65536
#define PFRAG_N 512

__device__ __forceinline__ void cvt2pack(float a, float b, unsigned* hw, unsigned* lw) {
    unsigned ua = __float_as_uint(a), ub = __float_as_uint(b);
    unsigned ha = (ua + 0x7fffu + ((ua >> 16) & 1u)) >> 16;
    unsigned hb = (ub + 0x7fffu + ((ub >> 16) & 1u)) >> 16;
    *hw = ha | (hb << 16);
    float ra = a - __uint_as_float(ha << 16);     // exact residual
    float rb = b - __uint_as_float(hb << 16);
    unsigned la = __float_as_uint(ra), lb = __float_as_uint(rb);
    unsigned l16a = (la + 0x7fffu + ((la >> 16) & 1u)) >> 16;
    unsigned l16b = (lb + 0x7fffu + ((lb >> 16) & 1u)) >> 16;
    *lw = l16a | (l16b << 16);
}

// ---------------- Kernel A: convert + per-row scalars ----------------
__global__ __launch_bounds__(256) void geodesic_convert(
    const float* __restrict__ x,
    const float* __restrict__ p,
    void* __restrict__ ws)
{
    uint4* XH0 = (uint4*)ws;
    uint4* XH1 = XH0 + XFRAG_N;
    uint4* XL0 = XH1 + XFRAG_N;
    uint4* XL1 = XL0 + XFRAG_N;
    float* x2f = (float*)(XL1 + XFRAG_N);
    uint4* PH0 = (uint4*)(x2f + 16384);
    uint4* PH1 = PH0 + PFRAG_N;
    uint4* PL0 = PH1 + PFRAG_N;
    uint4* PL1 = PL0 + PFRAG_N;
    float* p2f = (float*)(PL1 + PFRAG_N);

    const int tid = blockIdx.x * 256 + threadIdx.x;

    if (blockIdx.x < 256) {
        // ---- x: thread = one quarter-row (16 consecutive floats) ----
        const int row = tid >> 2;
        const int dq  = (tid & 3) << 4;
        const float* xr = x + (size_t)tid * 16;   // == row*64 + dq
        float4 v0 = *(const float4*)(xr);
        float4 v1 = *(const float4*)(xr + 4);
        float4 v2 = *(const float4*)(xr + 8);
        float4 v3 = *(const float4*)(xr + 12);

        float s = v0.x*v0.x + v0.y*v0.y + v0.z*v0.z + v0.w*v0.w
                + v1.x*v1.x + v1.y*v1.y + v1.z*v1.z + v1.w*v1.w
                + v2.x*v2.x + v2.y*v2.y + v2.z*v2.z + v2.w*v2.w
                + v3.x*v3.x + v3.y*v3.y + v3.z*v3.z + v3.w*v3.w;
        s += __shfl_xor(s, 1);
        s += __shfl_xor(s, 2);                    // full-row ||x||^2

        unsigned h[8], l[8];
        cvt2pack(v0.x, v0.y, &h[0], &l[0]);
        cvt2pack(v0.z, v0.w, &h[1], &l[1]);
        cvt2pack(v1.x, v1.y, &h[2], &l[2]);
        cvt2pack(v1.z, v1.w, &h[3], &l[3]);
        cvt2pack(v2.x, v2.y, &h[4], &l[4]);
        cvt2pack(v2.z, v2.w, &h[5], &l[5]);
        cvt2pack(v3.x, v3.y, &h[6], &l[6]);
        cvt2pack(v3.z, v3.w, &h[7], &l[7]);

        const int g   = row >> 4;
        const int m16 = row & 15;
        const int c0  = dq >> 3;                  // 0,2,4,6
        const int c1  = c0 + 1;
        const int i0  = g * 64 + (c0 & 3) * 16 + m16;
        const int i1  = g * 64 + (c1 & 3) * 16 + m16;
        uint4 hv0 = {h[0], h[1], h[2], h[3]};
        uint4 lv0 = {l[0], l[1], l[2], l[3]};
        uint4 hv1 = {h[4], h[5], h[6], h[7]};
        uint4 lv1 = {l[4], l[5], l[6], l[7]};
        ((c0 >> 2) ? XH1 : XH0)[i0] = hv0;
        ((c0 >> 2) ? XL1 : XL0)[i0] = lv0;
        ((c1 >> 2) ? XH1 : XH0)[i1] = hv1;
        ((c1 >> 2) ? XL1 : XL0)[i1] = lv1;
        if ((tid & 3) == 0) x2f[row] = s;
    } else {
        // ---- p: 512 quarter-rows; fold projection scale into stored bf16 ----
        const int ptid = tid - 65536;
        if (ptid >= 512) return;
        const int row = ptid >> 2;
        const int dq  = (ptid & 3) << 4;
        const float* pr = p + (size_t)ptid * 16;
        float4 v0 = *(const float4*)(pr);
        float4 v1 = *(const float4*)(pr + 4);
        float4 v2 = *(const float4*)(pr + 8);
        float4 v3 = *(const float4*)(pr + 12);

        float s = v0.x*v0.x + v0.y*v0.y + v0.z*v0.z + v0.w*v0.w
                + v1.x*v1.x + v1.y*v1.y + v1.z*v1.z + v1.w*v1.w
                + v2.x*v2.x + v2.y*v2.y + v2.z*v2.z + v2.w*v2.w
                + v3.x*v3.x + v3.y*v3.y + v3.z*v3.z + v3.w*v3.w;
        s += __shfl_xor(s, 1);
        s += __shfl_xor(s, 2);                    // full-row ||p||^2

        float nrm = fmaxf(sqrtf(s), 1e-15f);
        float sc  = fminf(1.0f, 0.999f / nrm);    // (1-BALL_EPS)/sqrt(c)
        v0.x*=sc; v0.y*=sc; v0.z*=sc; v0.w*=sc;
        v1.x*=sc; v1.y*=sc; v1.z*=sc; v1.w*=sc;
        v2.x*=sc; v2.y*=sc; v2.z*=sc; v2.w*=sc;
        v3.x*=sc; v3.y*=sc; v3.z*=sc; v3.w*=sc;

        unsigned h[8], l[8];
        cvt2pack(v0.x, v0.y, &h[0], &l[0]);
        cvt2pack(v0.z, v0.w, &h[1], &l[1]);
        cvt2pack(v1.x, v1.y, &h[2], &l[2]);
        cvt2pack(v1.z, v1.w, &h[3], &l[3]);
        cvt2pack(v2.x, v2.y, &h[4], &l[4]);
        cvt2pack(v2.z, v2.w, &h[5], &l[5]);
        cvt2pack(v3.x, v3.y, &h[6], &l[6]);
        cvt2pack(v3.z, v3.w, &h[7], &l[7]);

        const int kt  = row >> 4;
        const int m16 = row & 15;
        const int c0  = dq >> 3;
        const int c1  = c0 + 1;
        const int i0  = kt * 64 + (c0 & 3) * 16 + m16;
        const int i1  = kt * 64 + (c1 & 3) * 16 + m16;
        uint4 hv0 = {h[0], h[1], h[2], h[3]};
        uint4 lv0 = {l[0], l[1], l[2], l[3]};
        uint4 hv1 = {h[4], h[5], h[6], h[7]};
        uint4 lv1 = {l[4], l[5], l[6], l[7]};
        ((c0 >> 2) ? PH1 : PH0)[i0] = hv0;
        ((c0 >> 2) ? PL1 : PL0)[i0] = lv0;
        ((c1 >> 2) ? PH1 : PH0)[i1] = hv1;
        ((c1 >> 2) ? PL1 : PL0)[i1] = lv1;
        if ((ptid & 3) == 0) p2f[row] = s * sc * sc;
    }
}

// ---------------- Kernel B: MFMA + epilogue (no LDS, no barriers) ----------------
__global__ __launch_bounds__(256) void geodesic_compute(
    const void* __restrict__ ws,
    float* __restrict__ out)
{
    const uint4* XH0 = (const uint4*)ws;
    const uint4* XH1 = XH0 + XFRAG_N;
    const uint4* XL0 = XH1 + XFRAG_N;
    const uint4* XL1 = XL0 + XFRAG_N;
    const float* x2f = (const float*)(XL1 + XFRAG_N);
    const uint4* PH0 = (const uint4*)(x2f + 16384);
    const uint4* PH1 = PH0 + PFRAG_N;
    const uint4* PL0 = PH1 + PFRAG_N;
    const uint4* PL1 = PL0 + PFRAG_N;
    const float* p2f = (const float*)(PL1 + PFRAG_N);

    const int t    = threadIdx.x;
    const int g    = blockIdx.x;        // row-group: rows g*16..+15
    const int w    = t >> 6;            // wave -> k-quarter w*32..+32
    const int lane = t & 63;
    const int m16  = lane & 15;
    const int q    = lane >> 4;

    const int base = g * 64 + lane;
    bf16x8 xh0 = *(const bf16x8*)(&XH0[base]);
    bf16x8 xh1 = *(const bf16x8*)(&XH1[base]);
    bf16x8 xl0 = *(const bf16x8*)(&XL0[base]);
    bf16x8 xl1 = *(const bf16x8*)(&XL1[base]);

    float x2v[4];
    #pragma unroll
    for (int r = 0; r < 4; ++r) x2v[r] = x2f[g * 16 + q * 4 + r];

    #pragma unroll
    for (int kk = 0; kk < 2; ++kk) {
        const int kt = 2 * w + kk;
        const int pb = kt * 64 + lane;
        bf16x8 ph0 = *(const bf16x8*)(&PH0[pb]);
        bf16x8 ph1 = *(const bf16x8*)(&PH1[pb]);
        bf16x8 pl0 = *(const bf16x8*)(&PL0[pb]);
        bf16x8 pl1 = *(const bf16x8*)(&PL1[pb]);

        f32x4 acc = {0.f, 0.f, 0.f, 0.f};
        acc = __builtin_amdgcn_mfma_f32_16x16x32_bf16(xh0, ph0, acc, 0, 0, 0);
        acc = __builtin_amdgcn_mfma_f32_16x16x32_bf16(xh1, ph1, acc, 0, 0, 0);
        acc = __builtin_amdgcn_mfma_f32_16x16x32_bf16(xh0, pl0, acc, 0, 0, 0);
        acc = __builtin_amdgcn_mfma_f32_16x16x32_bf16(xh1, pl1, acc, 0, 0, 0);
        acc = __builtin_amdgcn_mfma_f32_16x16x32_bf16(xl0, ph0, acc, 0, 0, 0);
        acc = __builtin_amdgcn_mfma_f32_16x16x32_bf16(xl1, ph1, acc, 0, 0, 0);

        const float p2 = p2f[kt * 16 + m16];
        #pragma unroll
        for (int r = 0; r < 4; ++r) {
            const float x2 = x2v[r];
            const float xy = acc[r];             // projection already folded
            const float aa = 1.0f - 2.0f * xy + p2;
            const float bb = 1.0f - x2;
            const float den = fmaxf(1.0f - 2.0f * xy + x2 * p2, 1e-15f);
            const float n2 = fmaxf(aa*aa*x2 - 2.0f*aa*bb*xy + bb*bb*p2, 0.0f);
            const float sv = fminf(sqrtf(n2), 0.99999f * den);
            const float lg = __logf(__fdividef(den + sv, den - sv));
            out[(size_t)(g * 16 + q * 4 + r) * K_PROTO + kt * 16 + m16] = -(lg * lg);
        }
    }
}

extern "C" void kernel_launch(void* const* d_in, const int* in_sizes, int n_in,
                              void* d_out, int out_size, void* d_ws, size_t ws_size,
                              hipStream_t stream) {
    const float* x = (const float*)d_in[0];   // (16384, 64) f32
    const float* p = (const float*)d_in[1];   // (128, 64) f32
    float* out = (float*)d_out;               // (16384, 128) f32

    hipLaunchKernelGGL(geodesic_convert, dim3(258), dim3(256), 0, stream, x, p, d_ws);
    hipLaunchKernelGGL(geodesic_compute, dim3(1024), dim3(256), 0, stream, d_ws, out);
}